// Round 1
// baseline (357.813 us; speedup 1.0000x reference)
//
#include <hip/hip_runtime.h>

// FeaStNet NeighbourAssignment, restructured:
//   ST[i][0:8]=s_i, ST[i][8:16]=t_i
//   Q[e][m] = softmax_m(s[dst[e]][m] + t[src[e]][m])
//   G[i][m][c] = sum_{e: dst=i} Q[e][m] * x[src[e]][c]
//   R[i][m]    = sum_{e: dst=i} Q[e][m]
//   out[i][o]  = (1/8) * ( sum_{m,c} G[i][m][c]*W[m][c][o] + sum_m R[i][m]*b[m][o] )

#define CDIM 64
#define SDIM 8

__global__ __launch_bounds__(256) void k1_st(
    const float* __restrict__ x, const float* __restrict__ Ws,
    const float* __restrict__ bs, const float* __restrict__ Wt,
    const float* __restrict__ bt, float* __restrict__ ST, int N) {
  int tid = blockIdx.x * 256 + threadIdx.x;
  int i = tid >> 4, m = tid & 15;
  if (i >= N) return;
  int mm = m & 7;
  const float* Wp = (m < 8) ? Ws : Wt;
  float acc = (m < 8) ? bs[mm] : bt[mm];
  const float* xr = x + (size_t)i * CDIM;
#pragma unroll
  for (int c = 0; c < CDIM; ++c) acc += xr[c] * Wp[c * SDIM + mm];
  ST[i * 16 + m] = acc;
}

__global__ __launch_bounds__(256) void k2_q(
    const float* __restrict__ ST, const int* __restrict__ src,
    const int* __restrict__ dst, float* __restrict__ Q, int E) {
  int e = blockIdx.x * 256 + threadIdx.x;
  if (e >= E) return;
  int d = dst[e], j = src[e];
  const float* sd = ST + (size_t)d * 16;
  const float* tj = ST + (size_t)j * 16 + 8;
  float z[8];
  float mx = -1e30f;
#pragma unroll
  for (int m = 0; m < 8; ++m) {
    z[m] = sd[m] + tj[m];
    mx = fmaxf(mx, z[m]);
  }
  float sum = 0.f;
#pragma unroll
  for (int m = 0; m < 8; ++m) {
    z[m] = __expf(z[m] - mx);
    sum += z[m];
  }
  float inv = 1.0f / sum;
  float4* Qo = (float4*)(Q + (size_t)e * 8);
  Qo[0] = make_float4(z[0] * inv, z[1] * inv, z[2] * inv, z[3] * inv);
  Qo[1] = make_float4(z[4] * inv, z[5] * inv, z[6] * inv, z[7] * inv);
}

__device__ __forceinline__ int lower_bound_dst(const int* __restrict__ dst,
                                               int lo, int hi, int key) {
  // first index e in [lo,hi) with dst[e] >= key
  while (lo < hi) {
    int mid = (lo + hi) >> 1;
    if (dst[mid] < key) lo = mid + 1; else hi = mid;
  }
  return lo;
}

__global__ __launch_bounds__(256) void k3_gather(
    const float* __restrict__ x, const int* __restrict__ src,
    const int* __restrict__ dst, const float* __restrict__ Q,
    float* __restrict__ G, float* __restrict__ R, int N, int E) {
  int wave = __builtin_amdgcn_readfirstlane(threadIdx.x >> 6);
  int lane = threadIdx.x & 63;
  int i = blockIdx.x * 4 + wave;
  if (i >= N) return;

  int lo = lower_bound_dst(dst, 0, E, i);
  int hi = lower_bound_dst(dst, lo, E, i + 1);

  float g0 = 0, g1 = 0, g2 = 0, g3 = 0, g4 = 0, g5 = 0, g6 = 0, g7 = 0;
  float r0 = 0, r1 = 0, r2 = 0, r3 = 0, r4 = 0, r5 = 0, r6 = 0, r7 = 0;

  int e = lo;
  for (; e + 2 <= hi; e += 2) {
    int j0 = src[e];
    int j1 = src[e + 1];
    float4 qa0 = *(const float4*)(Q + (size_t)e * 8);
    float4 qb0 = *(const float4*)(Q + (size_t)e * 8 + 4);
    float4 qa1 = *(const float4*)(Q + (size_t)(e + 1) * 8);
    float4 qb1 = *(const float4*)(Q + (size_t)(e + 1) * 8 + 4);
    float xv0 = x[(size_t)j0 * CDIM + lane];
    float xv1 = x[(size_t)j1 * CDIM + lane];
    g0 += qa0.x * xv0; g1 += qa0.y * xv0; g2 += qa0.z * xv0; g3 += qa0.w * xv0;
    g4 += qb0.x * xv0; g5 += qb0.y * xv0; g6 += qb0.z * xv0; g7 += qb0.w * xv0;
    r0 += qa0.x; r1 += qa0.y; r2 += qa0.z; r3 += qa0.w;
    r4 += qb0.x; r5 += qb0.y; r6 += qb0.z; r7 += qb0.w;
    g0 += qa1.x * xv1; g1 += qa1.y * xv1; g2 += qa1.z * xv1; g3 += qa1.w * xv1;
    g4 += qb1.x * xv1; g5 += qb1.y * xv1; g6 += qb1.z * xv1; g7 += qb1.w * xv1;
    r0 += qa1.x; r1 += qa1.y; r2 += qa1.z; r3 += qa1.w;
    r4 += qb1.x; r5 += qb1.y; r6 += qb1.z; r7 += qb1.w;
  }
  if (e < hi) {
    int j0 = src[e];
    float4 qa0 = *(const float4*)(Q + (size_t)e * 8);
    float4 qb0 = *(const float4*)(Q + (size_t)e * 8 + 4);
    float xv0 = x[(size_t)j0 * CDIM + lane];
    g0 += qa0.x * xv0; g1 += qa0.y * xv0; g2 += qa0.z * xv0; g3 += qa0.w * xv0;
    g4 += qb0.x * xv0; g5 += qb0.y * xv0; g6 += qb0.z * xv0; g7 += qb0.w * xv0;
    r0 += qa0.x; r1 += qa0.y; r2 += qa0.z; r3 += qa0.w;
    r4 += qb0.x; r5 += qb0.y; r6 += qb0.z; r7 += qb0.w;
  }

  float* Gi = G + (size_t)i * 512;
  Gi[0 * 64 + lane] = g0; Gi[1 * 64 + lane] = g1;
  Gi[2 * 64 + lane] = g2; Gi[3 * 64 + lane] = g3;
  Gi[4 * 64 + lane] = g4; Gi[5 * 64 + lane] = g5;
  Gi[6 * 64 + lane] = g6; Gi[7 * 64 + lane] = g7;
  if (lane == 0) {
    float* Ri = R + (size_t)i * 8;
    Ri[0] = r0; Ri[1] = r1; Ri[2] = r2; Ri[3] = r3;
    Ri[4] = r4; Ri[5] = r5; Ri[6] = r6; Ri[7] = r7;
  }
}

__global__ __launch_bounds__(256) void k4_gemm(
    const float* __restrict__ G, const float* __restrict__ R,
    const float* __restrict__ W, const float* __restrict__ b,
    float* __restrict__ out, int N) {
  int wave = __builtin_amdgcn_readfirstlane(threadIdx.x >> 6);
  int lane = threadIdx.x & 63;
  int i0 = (blockIdx.x * 4 + wave) * 8;
  if (i0 >= N) return;

  float acc[8] = {0, 0, 0, 0, 0, 0, 0, 0};
  for (int k0 = 0; k0 < 512; k0 += 8) {
    float w[8];
#pragma unroll
    for (int kk = 0; kk < 8; ++kk) w[kk] = W[(size_t)(k0 + kk) * 64 + lane];
#pragma unroll
    for (int r = 0; r < 8; ++r) {
      int ri = i0 + r; ri = (ri < N) ? ri : (N - 1);
      const float* Gr = G + (size_t)ri * 512 + k0;
#pragma unroll
      for (int kk = 0; kk < 8; ++kk) acc[r] += Gr[kk] * w[kk];
    }
  }
#pragma unroll
  for (int r = 0; r < 8; ++r) {
    int ri = i0 + r;
    if (ri >= N) break;
    float a = acc[r];
    const float* Ri = R + (size_t)ri * 8;
#pragma unroll
    for (int m = 0; m < 8; ++m) a += Ri[m] * b[(size_t)m * 64 + lane];
    out[(size_t)ri * 64 + lane] = a * 0.125f;
  }
}

extern "C" void kernel_launch(void* const* d_in, const int* in_sizes, int n_in,
                              void* d_out, int out_size, void* d_ws, size_t ws_size,
                              hipStream_t stream) {
  const float* x  = (const float*)d_in[0];   // [N,64]
  const int* src  = (const int*)d_in[1];     // [E]
  const int* dst  = (const int*)d_in[2];     // [E] sorted
  const float* W  = (const float*)d_in[3];   // [8,64,64]
  const float* b  = (const float*)d_in[4];   // [8,64]
  const float* Ws = (const float*)d_in[5];   // [64,8]
  const float* bs = (const float*)d_in[6];   // [8]
  const float* Wt = (const float*)d_in[7];   // [64,8]
  const float* bt = (const float*)d_in[8];   // [8]
  int N = in_sizes[0] / CDIM;
  int E = in_sizes[1];
  float* out = (float*)d_out;

  float* ST = (float*)d_ws;                  // N*16
  float* Q  = ST + (size_t)N * 16;           // E*8
  float* G  = Q + (size_t)E * 8;             // N*512
  float* R  = G + (size_t)N * 512;           // N*8

  k1_st<<<(N * 16 + 255) / 256, 256, 0, stream>>>(x, Ws, bs, Wt, bt, ST, N);
  k2_q<<<(E + 255) / 256, 256, 0, stream>>>(ST, src, dst, Q, E);
  k3_gather<<<(N + 3) / 4, 256, 0, stream>>>(x, src, dst, Q, G, R, N, E);
  k4_gemm<<<(N + 31) / 32, 256, 0, stream>>>(G, R, W, b, out, N);
}

// Round 2
// 308.265 us; speedup vs baseline: 1.1607x; 1.1607x over previous
//
#include <hip/hip_runtime.h>

// FeaStNet NeighbourAssignment, restructured:
//   ST[i][0:8]=s_i, ST[i][8:16]=t_i
//   Q[e][m] = softmax_m(s[dst[e]][m] + t[src[e]][m])
//   rowptr[i] = first edge e with dst[e] >= i   (dst sorted)
//   G[i][m][c] = sum_{e in seg(i)} Q[e][m] * x[src[e]][c]
//   R[i][m]    = sum_{e in seg(i)} Q[e][m]
//   out[i][o]  = (1/8) * ( sum_{m,c} G[i][m][c]*W[m][c][o] + sum_m R[i][m]*b[m][o] )

#define CDIM 64
#define SDIM 8

__global__ __launch_bounds__(256) void k0_rowptr(
    const int* __restrict__ dst, int* __restrict__ rowptr, int N, int E) {
  int e = blockIdx.x * 256 + threadIdx.x;
  if (e >= E) return;
  int a = dst[e];
  int bnd = (e + 1 < E) ? dst[e + 1] : N;
  if (e == 0) {
    for (int d = 0; d <= a; ++d) rowptr[d] = 0;
  }
  for (int d = a + 1; d <= bnd; ++d) rowptr[d] = e + 1;
}

__global__ __launch_bounds__(256) void k1_st(
    const float* __restrict__ x, const float* __restrict__ Ws,
    const float* __restrict__ bs, const float* __restrict__ Wt,
    const float* __restrict__ bt, float* __restrict__ ST, int N) {
  int tid = blockIdx.x * 256 + threadIdx.x;
  int i = tid >> 4, m = tid & 15;
  if (i >= N) return;
  int mm = m & 7;
  const float* Wp = (m < 8) ? Ws : Wt;
  float acc = (m < 8) ? bs[mm] : bt[mm];
  const float* xr = x + (size_t)i * CDIM;
#pragma unroll
  for (int c = 0; c < CDIM; ++c) acc += xr[c] * Wp[c * SDIM + mm];
  ST[i * 16 + m] = acc;
}

__global__ __launch_bounds__(256) void k2_q(
    const float* __restrict__ ST, const int* __restrict__ src,
    const int* __restrict__ dst, float* __restrict__ Q, int E) {
  int e = blockIdx.x * 256 + threadIdx.x;
  if (e >= E) return;
  int d = dst[e], j = src[e];
  const float* sd = ST + (size_t)d * 16;
  const float* tj = ST + (size_t)j * 16 + 8;
  float z[8];
  float mx = -1e30f;
#pragma unroll
  for (int m = 0; m < 8; ++m) {
    z[m] = sd[m] + tj[m];
    mx = fmaxf(mx, z[m]);
  }
  float sum = 0.f;
#pragma unroll
  for (int m = 0; m < 8; ++m) {
    z[m] = __expf(z[m] - mx);
    sum += z[m];
  }
  float inv = 1.0f / sum;
  float4* Qo = (float4*)(Q + (size_t)e * 8);
  Qo[0] = make_float4(z[0] * inv, z[1] * inv, z[2] * inv, z[3] * inv);
  Qo[1] = make_float4(z[4] * inv, z[5] * inv, z[6] * inv, z[7] * inv);
}

__global__ __launch_bounds__(256) void k3_gather(
    const float* __restrict__ x, const int* __restrict__ src,
    const int* __restrict__ rowptr, const float* __restrict__ Q,
    float* __restrict__ G, float* __restrict__ R, int N) {
  int wave = __builtin_amdgcn_readfirstlane(threadIdx.x >> 6);
  int lane = threadIdx.x & 63;
  int i = blockIdx.x * 4 + wave;
  if (i >= N) return;

  int lo = rowptr[i];
  int hi = rowptr[i + 1];

  float g[8] = {0, 0, 0, 0, 0, 0, 0, 0};
  float r[8] = {0, 0, 0, 0, 0, 0, 0, 0};

  int deg = hi - lo;
  int emain_end = lo + (deg & ~7);

  if (deg >= 8) {
    int idx[8];
#pragma unroll
    for (int k = 0; k < 8; ++k) idx[k] = src[lo + k];

    for (int e0 = lo; e0 < emain_end; e0 += 8) {
      // issue this batch's 8 x-gathers first (8 loads in flight)
      float xv[8];
#pragma unroll
      for (int k = 0; k < 8; ++k) xv[k] = x[(size_t)idx[k] * CDIM + lane];

      // prefetch next batch's indices while x-gathers are in flight
      int nidx[8];
      int nbase = (e0 + 8 < emain_end) ? (e0 + 8) : lo;
#pragma unroll
      for (int k = 0; k < 8; ++k) nidx[k] = src[nbase + k];

      // Q for the batch: 256 B contiguous, wave-uniform
#pragma unroll
      for (int k = 0; k < 8; ++k) {
        const float* q = Q + (size_t)(e0 + k) * 8;
#pragma unroll
        for (int m = 0; m < 8; ++m) {
          float qv = q[m];
          g[m] = fmaf(qv, xv[k], g[m]);
          r[m] += qv;
        }
      }
#pragma unroll
      for (int k = 0; k < 8; ++k) idx[k] = nidx[k];
    }
  }

  // tail (< 8 edges)
  for (int e = emain_end; e < hi; ++e) {
    int j = src[e];
    float xv = x[(size_t)j * CDIM + lane];
    const float* q = Q + (size_t)e * 8;
#pragma unroll
    for (int m = 0; m < 8; ++m) {
      float qv = q[m];
      g[m] = fmaf(qv, xv, g[m]);
      r[m] += qv;
    }
  }

  float* Gi = G + (size_t)i * 512;
#pragma unroll
  for (int m = 0; m < 8; ++m) Gi[m * 64 + lane] = g[m];
  if (lane == 0) {
    float* Ri = R + (size_t)i * 8;
#pragma unroll
    for (int m = 0; m < 8; ++m) Ri[m] = r[m];
  }
}

__global__ __launch_bounds__(256) void k4_gemm(
    const float* __restrict__ G, const float* __restrict__ R,
    const float* __restrict__ W, const float* __restrict__ b,
    float* __restrict__ out, int N) {
  int wave = __builtin_amdgcn_readfirstlane(threadIdx.x >> 6);
  int lane = threadIdx.x & 63;
  int i0 = (blockIdx.x * 4 + wave) * 8;
  if (i0 >= N) return;

  float acc[8] = {0, 0, 0, 0, 0, 0, 0, 0};
  for (int k0 = 0; k0 < 512; k0 += 8) {
    float w[8];
#pragma unroll
    for (int kk = 0; kk < 8; ++kk) w[kk] = W[(size_t)(k0 + kk) * 64 + lane];
#pragma unroll
    for (int r = 0; r < 8; ++r) {
      int ri = i0 + r; ri = (ri < N) ? ri : (N - 1);
      const float* Gr = G + (size_t)ri * 512 + k0;
#pragma unroll
      for (int kk = 0; kk < 8; ++kk) acc[r] += Gr[kk] * w[kk];
    }
  }
#pragma unroll
  for (int r = 0; r < 8; ++r) {
    int ri = i0 + r;
    if (ri >= N) break;
    float a = acc[r];
    const float* Ri = R + (size_t)ri * 8;
#pragma unroll
    for (int m = 0; m < 8; ++m) a += Ri[m] * b[(size_t)m * 64 + lane];
    out[(size_t)ri * 64 + lane] = a * 0.125f;
  }
}

extern "C" void kernel_launch(void* const* d_in, const int* in_sizes, int n_in,
                              void* d_out, int out_size, void* d_ws, size_t ws_size,
                              hipStream_t stream) {
  const float* x  = (const float*)d_in[0];   // [N,64]
  const int* src  = (const int*)d_in[1];     // [E]
  const int* dst  = (const int*)d_in[2];     // [E] sorted
  const float* W  = (const float*)d_in[3];   // [8,64,64]
  const float* b  = (const float*)d_in[4];   // [8,64]
  const float* Ws = (const float*)d_in[5];   // [64,8]
  const float* bs = (const float*)d_in[6];   // [8]
  const float* Wt = (const float*)d_in[7];   // [64,8]
  const float* bt = (const float*)d_in[8];   // [8]
  int N = in_sizes[0] / CDIM;
  int E = in_sizes[1];
  float* out = (float*)d_out;

  float* ST = (float*)d_ws;                  // N*16 f32
  float* Q  = ST + (size_t)N * 16;           // E*8 f32
  float* G  = Q + (size_t)E * 8;             // N*512 f32
  float* R  = G + (size_t)N * 512;           // N*8 f32
  int* rowptr = (int*)(R + (size_t)N * 8);   // N+1 i32

  k0_rowptr<<<(E + 255) / 256, 256, 0, stream>>>(dst, rowptr, N, E);
  k1_st<<<(N * 16 + 255) / 256, 256, 0, stream>>>(x, Ws, bs, Wt, bt, ST, N);
  k2_q<<<(E + 255) / 256, 256, 0, stream>>>(ST, src, dst, Q, E);
  k3_gather<<<(N + 3) / 4, 256, 0, stream>>>(x, src, rowptr, Q, G, R, N);
  k4_gemm<<<(N + 31) / 32, 256, 0, stream>>>(G, R, W, b, out, N);
}